// Round 1
// baseline (290.807 us; speedup 1.0000x reference)
//
#include <hip/hip_runtime.h>
#include <hip/hip_bf16.h>

#define NN 4096
#define FIN 128
#define FOUT 64
#define NH 8
#define LOG2E 1.44269504088896340736f

typedef float f32x4 __attribute__((ext_vector_type(4)));
typedef __bf16 bf16x8 __attribute__((ext_vector_type(8)));

// ---------------- Kernel 0: fold skip_w over heads: Wf[i][f] = (1/8) sum_h skip_w[h*64+f][i]
__global__ __launch_bounds__(256) void fold_skip_kernel(
    const float* __restrict__ skip_w, float* __restrict__ Wf) {
    int idx = blockIdx.x * 256 + threadIdx.x;   // 8192 = 128*64
    int i = idx >> 6, f = idx & 63;
    float s = 0.f;
#pragma unroll
    for (int h = 0; h < NH; ++h) s += skip_w[(h * FOUT + f) * FIN + i];
    Wf[i * FOUT + f] = 0.125f * s;
}

// ---------------- Kernel 1: per-head projection h = x @ proj[h], emit:
//   Vt[h][f][n] (bf16, transposed for B-fragment loads)
//   ssrc[h][n], sdst[h][n]  (fp32, pre-scaled by log2e)
__global__ __launch_bounds__(256) void proj_kernel(
    const float* __restrict__ x, const float* __restrict__ proj,
    const float* __restrict__ sw_src, const float* __restrict__ sw_dst,
    __hip_bfloat16* __restrict__ Vt, float* __restrict__ ssrc, float* __restrict__ sdst) {
    __shared__ float ps[FIN][FOUT];        // 32 KB
    __shared__ float xs[32][FIN + 4];      // 16.9 KB, pad to break bank conflicts
    __shared__ float red_s[32], red_d[32];

    const int head = blockIdx.x & 7;
    const int n0 = (blockIdx.x >> 3) * 32;
    const int tid = threadIdx.x;

    // stage proj[head] (128x64) and x tile (32x128)
    const float4* psrc = (const float4*)(proj + (size_t)head * FIN * FOUT);
    float4* pdst = (float4*)&ps[0][0];
    for (int i = tid; i < FIN * FOUT / 4; i += 256) pdst[i] = psrc[i];
    const float4* xsrc = (const float4*)(x + (size_t)n0 * FIN);
    for (int i = tid; i < 32 * FIN / 4; i += 256) {
        int r = i >> 5, c4 = i & 31;
        *(float4*)&xs[r][c4 * 4] = xsrc[i];
    }
    if (tid < 32) { red_s[tid] = 0.f; red_d[tid] = 0.f; }
    __syncthreads();

    const int r = tid & 31;            // row within tile
    const int f0 = (tid >> 5) * 8;     // 8 output features per thread
    float acc[8];
#pragma unroll
    for (int j = 0; j < 8; ++j) acc[j] = 0.f;
#pragma unroll 4
    for (int i = 0; i < FIN; ++i) {
        float xv = xs[r][i];
        float4 p0 = *(float4*)&ps[i][f0];
        float4 p1 = *(float4*)&ps[i][f0 + 4];
        acc[0] += xv * p0.x; acc[1] += xv * p0.y; acc[2] += xv * p0.z; acc[3] += xv * p0.w;
        acc[4] += xv * p1.x; acc[5] += xv * p1.y; acc[6] += xv * p1.z; acc[7] += xv * p1.w;
    }
    // score partial dots
    float pssum = 0.f, pdsum = 0.f;
#pragma unroll
    for (int j = 0; j < 8; ++j) {
        pssum += acc[j] * sw_src[head * FOUT + f0 + j];
        pdsum += acc[j] * sw_dst[head * FOUT + f0 + j];
    }
    atomicAdd(&red_s[r], pssum);
    atomicAdd(&red_d[r], pdsum);
    // write Vt bf16: Vt[head][f][n]
#pragma unroll
    for (int j = 0; j < 8; ++j)
        Vt[((size_t)head * FOUT + f0 + j) * NN + n0 + r] = __float2bfloat16(acc[j]);
    __syncthreads();
    if (tid < 32) {
        ssrc[head * NN + n0 + tid] = LOG2E * red_s[tid];
        sdst[head * NN + n0 + tid] = LOG2E * red_d[tid];
    }
}

// ---------------- Kernel 2: skipm = x @ Wf   (mean-over-heads skip, [N][64] fp32)
__global__ __launch_bounds__(256) void skipm_kernel(
    const float* __restrict__ x, const float* __restrict__ Wf, float* __restrict__ skipm) {
    __shared__ float ws_[FIN][FOUT];
    __shared__ float xs[32][FIN + 4];
    const int n0 = blockIdx.x * 32;
    const int tid = threadIdx.x;
    const float4* psrc = (const float4*)Wf;
    float4* pdst = (float4*)&ws_[0][0];
    for (int i = tid; i < FIN * FOUT / 4; i += 256) pdst[i] = psrc[i];
    const float4* xsrc = (const float4*)(x + (size_t)n0 * FIN);
    for (int i = tid; i < 32 * FIN / 4; i += 256) {
        int r = i >> 5, c4 = i & 31;
        *(float4*)&xs[r][c4 * 4] = xsrc[i];
    }
    __syncthreads();
    const int r = tid & 31;
    const int f0 = (tid >> 5) * 8;
    float acc[8];
#pragma unroll
    for (int j = 0; j < 8; ++j) acc[j] = 0.f;
#pragma unroll 4
    for (int i = 0; i < FIN; ++i) {
        float xv = xs[r][i];
        float4 p0 = *(float4*)&ws_[i][f0];
        float4 p1 = *(float4*)&ws_[i][f0 + 4];
        acc[0] += xv * p0.x; acc[1] += xv * p0.y; acc[2] += xv * p0.z; acc[3] += xv * p0.w;
        acc[4] += xv * p1.x; acc[5] += xv * p1.y; acc[6] += xv * p1.z; acc[7] += xv * p1.w;
    }
#pragma unroll
    for (int j = 0; j < 8; ++j)
        skipm[(size_t)(n0 + r) * FOUT + f0 + j] = acc[j];
}

// ---------------- Kernel 3: flash-style GAT attention, all 8 heads per block.
// Block: 512 threads (8 waves); wave w owns head w. Query tile = 16 rows.
// Online softmax in log2 domain; P,V in bf16 via mfma_f32_16x16x32_bf16.
__global__ __launch_bounds__(512) void attn_kernel(
    const float* __restrict__ topo, const __hip_bfloat16* __restrict__ Vt_,
    const float* __restrict__ ssrc, const float* __restrict__ sdst,
    const float* __restrict__ skipm, float* __restrict__ out) {
    __shared__ float topoS[16][68];          // padded: stride 68 floats
    __shared__ float stageO[NH][16][68];     // per-head normalized O tiles

    const int tid = threadIdx.x;
    const int wave = tid >> 6;               // = head
    const int lane = tid & 63;
    const int q = lane >> 4;                 // quad 0..3
    const int li = lane & 15;                // row-in-tile / col-in-tile index
    const int q0 = blockIdx.x * 16;

    const __bf16* vbase = reinterpret_cast<const __bf16*>(Vt_) + (size_t)wave * FOUT * NN;
    const float* sdbase = sdst + wave * NN;
    const float ssrc_i = ssrc[wave * NN + q0 + li];   // log2e-scaled

    float m = -INFINITY, l = 0.f;
    f32x4 acc[4];
#pragma unroll
    for (int n = 0; n < 4; ++n) acc[n] = (f32x4){0.f, 0.f, 0.f, 0.f};

    for (int kt = 0; kt < NN / 64; ++kt) {
        __syncthreads();   // previous tile fully consumed
        {   // cooperative topo tile load (16x64), scaled by log2e
            int e = tid * 2;
            int rr = e >> 6, cc = e & 63;
            float2 tv = *(const float2*)&topo[(size_t)(q0 + rr) * NN + kt * 64 + cc];
            topoS[rr][cc] = tv.x * LOG2E;
            topoS[rr][cc + 1] = tv.y * LOG2E;
        }
        __syncthreads();

        // per-lane slices: keys k = kt*64 + c*32 + q*8 + j
        const float* sd = sdbase + kt * 64 + q * 8;
        float sdv[16], tvv[16];
        *(float4*)(sdv + 0)  = *(const float4*)(sd + 0);
        *(float4*)(sdv + 4)  = *(const float4*)(sd + 4);
        *(float4*)(sdv + 8)  = *(const float4*)(sd + 32);
        *(float4*)(sdv + 12) = *(const float4*)(sd + 36);
        const float* tr = &topoS[li][q * 8];
        *(float4*)(tvv + 0)  = *(const float4*)(tr + 0);
        *(float4*)(tvv + 4)  = *(const float4*)(tr + 4);
        *(float4*)(tvv + 8)  = *(const float4*)(tr + 32);
        *(float4*)(tvv + 12) = *(const float4*)(tr + 36);

        // V B-fragments: lane holds V[k][f = n*16+li], k = q*8+j (contiguous in Vt row)
        bf16x8 vf[2][4];
#pragma unroll
        for (int n = 0; n < 4; ++n) {
            const __bf16* vp = vbase + (size_t)(n * 16 + li) * NN + kt * 64 + q * 8;
            vf[0][n] = *(const bf16x8*)(vp);
            vf[1][n] = *(const bf16x8*)(vp + 32);
        }

        // scores (log2 domain): s = LR(ssrc+sdst) + topo'
        float sb[16];
#pragma unroll
        for (int e = 0; e < 16; ++e) {
            float t = ssrc_i + sdv[e];
            sb[e] = fmaxf(t, 0.2f * t) + tvv[e];
        }
        float mt = sb[0];
#pragma unroll
        for (int e = 1; e < 16; ++e) mt = fmaxf(mt, sb[e]);
        mt = fmaxf(mt, __shfl_xor(mt, 16));
        mt = fmaxf(mt, __shfl_xor(mt, 32));
        float mnew = fmaxf(m, mt);
        float alpha = exp2f(m - mnew);     // m=-inf first iter -> alpha=0

        float rs = 0.f;
        bf16x8 pf[2];
#pragma unroll
        for (int c = 0; c < 2; ++c) {
#pragma unroll
            for (int j = 0; j < 8; ++j) {
                float p = exp2f(sb[c * 8 + j] - mnew);   // subtract FIRST (masked ~ -1.4e9)
                rs += p;
                pf[c][j] = (__bf16)p;
            }
        }
        rs += __shfl_xor(rs, 16);
        rs += __shfl_xor(rs, 32);
        l = l * alpha + rs;
        m = mnew;

        // rescale accumulators; C-layout row = q*4+reg, so fetch those rows' alphas
        float a0 = __shfl(alpha, q * 4 + 0);
        float a1 = __shfl(alpha, q * 4 + 1);
        float a2 = __shfl(alpha, q * 4 + 2);
        float a3 = __shfl(alpha, q * 4 + 3);
#pragma unroll
        for (int n = 0; n < 4; ++n) {
            acc[n][0] *= a0; acc[n][1] *= a1; acc[n][2] *= a2; acc[n][3] *= a3;
        }
#pragma unroll
        for (int c = 0; c < 2; ++c)
#pragma unroll
            for (int n = 0; n < 4; ++n)
                acc[n] = __builtin_amdgcn_mfma_f32_16x16x32_bf16(pf[c], vf[c][n], acc[n], 0, 0, 0);
    }

    // epilogue: normalize by l (per C-layout row), stage per-head tiles to LDS
    float l0 = __shfl(l, q * 4 + 0);
    float l1 = __shfl(l, q * 4 + 1);
    float l2 = __shfl(l, q * 4 + 2);
    float l3 = __shfl(l, q * 4 + 3);
    float r0 = 1.f / l0, r1 = 1.f / l1, r2 = 1.f / l2, r3 = 1.f / l3;
#pragma unroll
    for (int n = 0; n < 4; ++n) {
        stageO[wave][q * 4 + 0][n * 16 + li] = acc[n][0] * r0;
        stageO[wave][q * 4 + 1][n * 16 + li] = acc[n][1] * r1;
        stageO[wave][q * 4 + 2][n * 16 + li] = acc[n][2] * r2;
        stageO[wave][q * 4 + 3][n * 16 + li] = acc[n][3] * r3;
    }
    __syncthreads();

    // mean over heads + skip + LeakyReLU, coalesced float2 stores
    {
        int e = tid * 2;
        int rr = e >> 6, cc = e & 63;
        float s0 = 0.f, s1 = 0.f;
#pragma unroll
        for (int h = 0; h < NH; ++h) {
            s0 += stageO[h][rr][cc];
            s1 += stageO[h][rr][cc + 1];
        }
        float2 sk = *(const float2*)&skipm[(size_t)(q0 + rr) * FOUT + cc];
        float v0 = s0 * 0.125f + sk.x;
        float v1 = s1 * 0.125f + sk.y;
        v0 = fmaxf(v0, 0.2f * v0);
        v1 = fmaxf(v1, 0.2f * v1);
        float2 o = {v0, v1};
        *(float2*)&out[(size_t)(q0 + rr) * FOUT + cc] = o;
    }
}

extern "C" void kernel_launch(void* const* d_in, const int* in_sizes, int n_in,
                              void* d_out, int out_size, void* d_ws, size_t ws_size,
                              hipStream_t stream) {
    (void)in_sizes; (void)n_in; (void)out_size; (void)ws_size;
    const float* x         = (const float*)d_in[0];   // [4096,128]
    const float* topology  = (const float*)d_in[1];   // [4096,4096]
    const float* proj      = (const float*)d_in[2];   // [8,128,64]
    const float* score_src = (const float*)d_in[3];   // [8,64]
    const float* score_dst = (const float*)d_in[4];   // [8,64]
    const float* skip_w    = (const float*)d_in[5];   // [512,128]
    float* out = (float*)d_out;                       // [4096,64]

    // workspace layout
    char* ws = (char*)d_ws;
    __hip_bfloat16* Vt = (__hip_bfloat16*)ws;                       // 8*64*4096*2 = 4 MB
    float* ssrc  = (float*)(ws + 4194304);                          // 128 KB
    float* sdst  = (float*)(ws + 4194304 + 131072);                 // 128 KB
    float* Wf    = (float*)(ws + 4194304 + 262144);                 // 32 KB
    float* skipm = (float*)(ws + 4194304 + 262144 + 32768);         // 1 MB

    fold_skip_kernel<<<32, 256, 0, stream>>>(skip_w, Wf);
    proj_kernel<<<1024, 256, 0, stream>>>(x, proj, score_src, score_dst, Vt, ssrc, sdst);
    skipm_kernel<<<128, 256, 0, stream>>>(x, Wf, skipm);
    attn_kernel<<<256, 512, 0, stream>>>(topology, Vt, ssrc, sdst, skipm, out);
}